// Round 10
// baseline (9353.452 us; speedup 1.0000x reference)
//
#include <hip/hip_runtime.h>
#include <math.h>

// CMmodel: two sparse-addressing memory units (cosine sim -> top-10 -> softmax(relu) -> gather)
// each followed by train-mode BatchNorm + LeakyReLU.  N=32768, D=256, MEM=2048, K=10.
// fp32 scoring on vector ALU (no fp32 MFMA on CDNA4). FMA-issue floor ~218 us/unit.
//
// ROUND-10: round 9 passed numerical validation but tripped the launch-once-vs-graph
// tripwire. Only nondeterminism: float atomicAdd ordering on BN column sums ->
// last-ulp BN-stat wobble. Fix: bitwise-deterministic two-phase stats reduction
// (stats_part_kernel partials to ws + stats_reduce_kernel fixed-order sum); all
// atomics removed. Kept from round 9 (validated, never profiled): waves_per_eu(2,2)
// 256-VGPR budget + fully scalarized hot arrays to kill the 13GB/dispatch spill
// traffic measured in rounds 3/8 (VGPR=128, VALUBusy 15%).
//
// Geometry: 512 thr = 8 waves/block, 64 rows/block, 1 block/CU (128 KiB LDS).
// Wave w owns rows w*8..w*8+7 (A-reads are wave-uniform LDS broadcasts); lane owns
// 4 contiguous cols of each 256-col chunk (B-reads: conflict-free 16B-stride b128).
// B staged in LDS with XOR swizzle  scol = col ^ (((k>>2)&7)<<3)  -> staging writes
// are 2-way (free); reads stay conflict-free (wave-uniform swizzle key).

#define NROWS 32768
#define DIM   256
#define MSIZE 2048
#define TK    10
#define BM    64
#define BN    256
#define KC    32
#define NKC   8      // DIM/KC
#define NCC   8      // MSIZE/BN
#define NTHR  512
#define SBLK  128    // stats phase-A blocks (256 rows each)
#define BNEPS 1e-5f
#define SLOPE 0.01f

union UMem {
  float ms[2][KC][BN];          // 64 KiB: double-buffered mem chunk [k][swizzled col], pre-scaled
  struct {                      // used after the GEMM phase (barrier-separated)
    float tw[8][8][TK];         // [wave][row-in-wave][e] softmax weights
    int   tx[8][8][TK];         // [wave][row-in-wave][e] gathered indices
  } f;
};

// gated register bubble-insert; strict > keeps earlier (lower-index) entries on ties
#define INSERT(LI, V, XI)                                               \
  do {                                                                  \
    const float v_ = (V);                                               \
    if (v_ > tv[LI][TK-1]) {                                            \
      float t_ = v_; int x_ = (XI);                                     \
      _Pragma("unroll")                                                 \
      for (int p_ = 0; p_ < TK; ++p_) {                                 \
        const bool  sw_ = (t_ > tv[LI][p_]);                            \
        const float ov_ = tv[LI][p_]; const int ox_ = ti_[LI][p_];      \
        tv[LI][p_]  = sw_ ? t_ : ov_;  ti_[LI][p_] = sw_ ? x_ : ox_;    \
        t_ = sw_ ? ov_ : t_;  x_ = sw_ ? ox_ : x_;                      \
      }                                                                  \
    }                                                                   \
  } while (0)

// one row's 4-col FMA against the shared b fragment
#define FMA_ROW(ACC, AV)                                                \
  ACC.x = fmaf((AV), b.x, ACC.x); ACC.y = fmaf((AV), b.y, ACC.y);       \
  ACC.z = fmaf((AV), b.z, ACC.z); ACC.w = fmaf((AV), b.w, ACC.w);

// one k-step (k4*4+J4) over all 8 rows; COMP selects the a-component (compile-time)
#define K4STEP(J4, COMP)                                                \
  { const float4 b = *reinterpret_cast<const float4*>(&u.ms[cur][k4*4 + (J4)][bcol]); \
    FMA_ROW(acc0, a_0.COMP) FMA_ROW(acc1, a_1.COMP)                     \
    FMA_ROW(acc2, a_2.COMP) FMA_ROW(acc3, a_3.COMP)                     \
    FMA_ROW(acc4, a_4.COMP) FMA_ROW(acc5, a_5.COMP)                     \
    FMA_ROW(acc6, a_6.COMP) FMA_ROW(acc7, a_7.COMP) }

// stage one (row, 4-k slice) piece: transposed + pre-scaled + swizzled
#define STAGE1(BUF, G, MC, SL)                                          \
  u.ms[BUF][kq*4+0][SL] = (G).x * (MC);                                 \
  u.ms[BUF][kq*4+1][SL] = (G).y * (MC);                                 \
  u.ms[BUF][kq*4+2][SL] = (G).z * (MC);                                 \
  u.ms[BUF][kq*4+3][SL] = (G).w * (MC);

__global__ void __launch_bounds__(NTHR)
__attribute__((amdgpu_waves_per_eu(2, 2)))
unit_kernel(
    const float* __restrict__ X,      // [NROWS][DIM]
    const float* __restrict__ M,      // [MSIZE][DIM]
    const float* __restrict__ Minv,   // [MSIZE] 1/||m_row||
    float* __restrict__ H)            // [NROWS][DIM] output (may alias X; tile staged first)
{
  __shared__ float xs[BM][DIM];       // 64 KiB row-major x tile, pre-scaled by 1/||x||
  __shared__ UMem u;

  const int  tid  = threadIdx.x;
  const int  w    = tid >> 6;         // wave 0..7 -> rows w*8..w*8+7
  const int  lane = tid & 63;
  const bool hi   = lane >= 32;
  const int  row0 = blockIdx.x * BM;

  // ---- stage X rows (coalesced 1KB/instr/wave), fused 1/||x|| scale ----
  #pragma unroll
  for (int p = 0; p < 8; ++p) {
    const int r = p * 8 + w;
    const float4 v = reinterpret_cast<const float4*>(X + (size_t)(row0 + r) * DIM)[lane];
    float s = v.x*v.x + v.y*v.y + v.z*v.z + v.w*v.w;
    #pragma unroll
    for (int m = 32; m >= 1; m >>= 1) s += __shfl_xor(s, m, 64);
    const float sc = 1.0f / sqrtf(s);
    const float4 o = {v.x*sc, v.y*sc, v.z*sc, v.w*sc};
    reinterpret_cast<float4*>(&xs[r][0])[lane] = o;   // 16B lane-stride: conflict-free
  }
  __syncthreads();

  // ---- per-lane top-10 for this lane's half-rows (lo: rows 0-3, hi: rows 4-7) ----
  float tv[4][TK]; int ti_[4][TK];
  #pragma unroll
  for (int i = 0; i < 4; ++i)
    #pragma unroll
    for (int p = 0; p < TK; ++p) { tv[i][p] = -INFINITY; ti_[i][p] = 0x7FFFFFFF; }

  // staging geometry (kc-invariant): kq = tid&7 selects the 4-k slice; swizzled col
  const int kq   = tid & 7;
  const int mrow = tid >> 3;                 // 0..63: mem row within 64-row group
  const int sl   = mrow ^ (kq << 3);         // swizzled LDS col (within 64-col group)
  const int sloc0 = sl, sloc1 = 64 + sl, sloc2 = 128 + sl, sloc3 = 192 + sl;

  for (int cc = 0; cc < NCC; ++cc) {
    const int col0 = cc * BN;

    const float mc0 = Minv[col0 + mrow];
    const float mc1 = Minv[col0 + 64 + mrow];
    const float mc2 = Minv[col0 + 128 + mrow];
    const float mc3 = Minv[col0 + 192 + mrow];
    const float4* msrc0 = reinterpret_cast<const float4*>(M + (size_t)(col0 +        mrow) * DIM) + kq;
    const float4* msrc1 = reinterpret_cast<const float4*>(M + (size_t)(col0 +  64 + mrow) * DIM) + kq;
    const float4* msrc2 = reinterpret_cast<const float4*>(M + (size_t)(col0 + 128 + mrow) * DIM) + kq;
    const float4* msrc3 = reinterpret_cast<const float4*>(M + (size_t)(col0 + 192 + mrow) * DIM) + kq;

    float4 acc0 = {0,0,0,0}, acc1 = {0,0,0,0}, acc2 = {0,0,0,0}, acc3 = {0,0,0,0};
    float4 acc4 = {0,0,0,0}, acc5 = {0,0,0,0}, acc6 = {0,0,0,0}, acc7 = {0,0,0,0};

    // prologue: stage k-chunk 0
    float4 g0 = msrc0[0], g1 = msrc1[0], g2 = msrc2[0], g3 = msrc3[0];
    STAGE1(0, g0, mc0, sloc0) STAGE1(0, g1, mc1, sloc1)
    STAGE1(0, g2, mc2, sloc2) STAGE1(0, g3, mc3, sloc3)
    __syncthreads();

    for (int kc = 0; kc < NKC; ++kc) {
      const int cur = kc & 1;
      if (kc < NKC - 1) {          // issue next chunk's global loads early
        g0 = msrc0[(kc + 1) * 8]; g1 = msrc1[(kc + 1) * 8];
        g2 = msrc2[(kc + 1) * 8]; g3 = msrc3[(kc + 1) * 8];
      }
      #pragma unroll
      for (int k4 = 0; k4 < KC/4; ++k4) {
        const int kbase = kc * KC + k4 * 4;  // wave-uniform broadcast reads
        const float4 a_0 = *reinterpret_cast<const float4*>(&xs[w*8 + 0][kbase]);
        const float4 a_1 = *reinterpret_cast<const float4*>(&xs[w*8 + 1][kbase]);
        const float4 a_2 = *reinterpret_cast<const float4*>(&xs[w*8 + 2][kbase]);
        const float4 a_3 = *reinterpret_cast<const float4*>(&xs[w*8 + 3][kbase]);
        const float4 a_4 = *reinterpret_cast<const float4*>(&xs[w*8 + 4][kbase]);
        const float4 a_5 = *reinterpret_cast<const float4*>(&xs[w*8 + 5][kbase]);
        const float4 a_6 = *reinterpret_cast<const float4*>(&xs[w*8 + 6][kbase]);
        const float4 a_7 = *reinterpret_cast<const float4*>(&xs[w*8 + 7][kbase]);
        const int bcol = (lane * 4) ^ (k4 << 3);   // un-swizzle: key k4 is wave-uniform
        K4STEP(0, x) K4STEP(1, y) K4STEP(2, z) K4STEP(3, w)
      }
      if (kc < NKC - 1) {          // write-late; one barrier per chunk
        const int nxt = cur ^ 1;
        STAGE1(nxt, g0, mc0, sloc0) STAGE1(nxt, g1, mc1, sloc1)
        STAGE1(nxt, g2, mc2, sloc2) STAGE1(nxt, g3, mc3, sloc3)
        __syncthreads();
      }
    }

    // ---- candidate exchange across half-waves, then gated top-10 insert ----
    // lo keeps rows 0-3 (gives rows 4-7); hi keeps rows 4-7 (gives rows 0-3)
    float4 gv0, gv1, gv2, gv3;
    {
      const float4 s0 = hi ? acc0 : acc4;
      const float4 s1 = hi ? acc1 : acc5;
      const float4 s2 = hi ? acc2 : acc6;
      const float4 s3 = hi ? acc3 : acc7;
      gv0.x = __shfl_xor(s0.x, 32, 64); gv0.y = __shfl_xor(s0.y, 32, 64);
      gv0.z = __shfl_xor(s0.z, 32, 64); gv0.w = __shfl_xor(s0.w, 32, 64);
      gv1.x = __shfl_xor(s1.x, 32, 64); gv1.y = __shfl_xor(s1.y, 32, 64);
      gv1.z = __shfl_xor(s1.z, 32, 64); gv1.w = __shfl_xor(s1.w, 32, 64);
      gv2.x = __shfl_xor(s2.x, 32, 64); gv2.y = __shfl_xor(s2.y, 32, 64);
      gv2.z = __shfl_xor(s2.z, 32, 64); gv2.w = __shfl_xor(s2.w, 32, 64);
      gv3.x = __shfl_xor(s3.x, 32, 64); gv3.y = __shfl_xor(s3.y, 32, 64);
      gv3.z = __shfl_xor(s3.z, 32, 64); gv3.w = __shfl_xor(s3.w, 32, 64);
    }
    const int ownc = col0 + lane * 4;
    const int gotc = col0 + (lane ^ 32) * 4;
    const int cA = hi ? gotc : ownc;   // always the lower col group -> ascending tie-break
    const int cB = hi ? ownc : gotc;
    #define INS_LIST(LI, GVI, AI, AI4)                                   \
      { const float4 fb = hi ? (GVI) : (AI); const float4 sb = hi ? (AI4) : (GVI); \
        INSERT(LI, fb.x, cA+0); INSERT(LI, fb.y, cA+1);                  \
        INSERT(LI, fb.z, cA+2); INSERT(LI, fb.w, cA+3);                  \
        INSERT(LI, sb.x, cB+0); INSERT(LI, sb.y, cB+1);                  \
        INSERT(LI, sb.z, cB+2); INSERT(LI, sb.w, cB+3); }
    INS_LIST(0, gv0, acc0, acc4)
    INS_LIST(1, gv1, acc1, acc5)
    INS_LIST(2, gv2, acc2, acc6)
    INS_LIST(3, gv3, acc3, acc7)
    #undef INS_LIST
  }
  __syncthreads();   // all u.ms reads done -> u.f alias safe

  // ---- merge 32 lanes' lists per row (both halves in lockstep), softmax, stash to LDS ----
  #pragma unroll
  for (int li = 0; li < 4; ++li) {
    float wv[TK]; int wx[TK];
    #pragma unroll
    for (int e = 0; e < TK; ++e) {
      float hv = tv[li][0]; int hx = ti_[li][0];
      #pragma unroll
      for (int m = 1; m <= 16; m <<= 1) {     // butterfly stays within each 32-lane half
        const float ov = __shfl_xor(hv, m, 64);
        const int   ox = __shfl_xor(hx, m, 64);
        const bool take = (ov > hv) || ((ov == hv) && (ox < hx));  // jax tie-break
        hv = take ? ov : hv; hx = take ? ox : hx;
      }
      wv[e] = hv; wx[e] = hx;
      if (ti_[li][0] == hx) {                 // winning lane pops its head (indices unique)
        #pragma unroll
        for (int p = 0; p < TK-1; ++p) { tv[li][p] = tv[li][p+1]; ti_[li][p] = ti_[li][p+1]; }
        tv[li][TK-1] = -INFINITY; ti_[li][TK-1] = 0x7FFFFFFF;
      }
    }
    // softmax(relu(S)); wv[0] is the max
    const float mx = fmaxf(wv[0], 0.f);
    float we[TK]; float ssum = 0.f;
    #pragma unroll
    for (int e = 0; e < TK; ++e) { we[e] = expf(fmaxf(wv[e], 0.f) - mx); ssum += we[e]; }
    const float winv = 1.0f / ssum;
    const int r8 = (hi ? 4 : 0) + li;
    if ((lane & 31) == 0) {
      #pragma unroll
      for (int e = 0; e < TK; ++e) { u.f.tw[w][r8][e] = we[e] * winv; u.f.tx[w][r8][e] = wx[e]; }
    }
  }
  __syncthreads();

  // ---- weighted gather (full wave per row, coalesced) + output write ----
  #pragma unroll
  for (int r8 = 0; r8 < 8; ++r8) {
    float h0 = 0.f, h1 = 0.f, h2 = 0.f, h3 = 0.f;
    #pragma unroll
    for (int e = 0; e < TK; ++e) {
      const float we = u.f.tw[w][r8][e];      // wave-uniform broadcast reads
      const int   xe = u.f.tx[w][r8][e];
      const float4 mv = reinterpret_cast<const float4*>(M + (size_t)xe * DIM)[lane];
      h0 = fmaf(we, mv.x, h0); h1 = fmaf(we, mv.y, h1);
      h2 = fmaf(we, mv.z, h2); h3 = fmaf(we, mv.w, h3);
    }
    const int row = row0 + w*8 + r8;
    const float4 o = {h0, h1, h2, h3};
    reinterpret_cast<float4*>(H + (size_t)row * DIM)[lane] = o;
  }
}

// ---------------- 1/||mem_row|| for both memories ----------------
__global__ void __launch_bounds__(256) memnorm_kernel(
    const float* __restrict__ m1, const float* __restrict__ m2,
    float* __restrict__ inv1, float* __restrict__ inv2)
{
  const int row  = blockIdx.x * 4 + (threadIdx.x >> 6);   // grid covers exactly 2*MSIZE rows
  const int lane = threadIdx.x & 63;
  const float* src = (row < MSIZE) ? m1 : m2;
  const int r = row & (MSIZE - 1);
  const float4 v = reinterpret_cast<const float4*>(src)[r * (DIM/4) + lane];
  float s = v.x*v.x + v.y*v.y + v.z*v.z + v.w*v.w;
  #pragma unroll
  for (int m = 32; m >= 1; m >>= 1) s += __shfl_xor(s, m, 64);
  if (lane == 0) ((row < MSIZE) ? inv1 : inv2)[r] = 1.0f / sqrtf(s);
}

// ---------------- deterministic BN stats, phase A: per-block column partials ----------------
__global__ void __launch_bounds__(256) stats_part_kernel(
    const float* __restrict__ H, float* __restrict__ part)   // part[SBLK][2][DIM]
{
  const int c = threadIdx.x;                 // column 0..255
  const int b = blockIdx.x;                  // 0..SBLK-1
  const int rows = NROWS / SBLK;             // 256 rows per block
  const float* p = H + (size_t)b * rows * DIM + c;
  float s = 0.f, q = 0.f;
  #pragma unroll 8
  for (int r = 0; r < rows; ++r) {           // fixed serial order: deterministic
    const float v = p[(size_t)r * DIM];
    s += v; q = fmaf(v, v, q);
  }
  part[(size_t)(b * 2 + 0) * DIM + c] = s;
  part[(size_t)(b * 2 + 1) * DIM + c] = q;
}

// ---------------- deterministic BN stats, phase B: fixed-order reduce ----------------
__global__ void __launch_bounds__(512) stats_reduce_kernel(
    const float* __restrict__ part, float* __restrict__ cs, float* __restrict__ cq)
{
  const int t  = threadIdx.x;
  const int c  = t & 255;
  const int sq = t >> 8;                     // 0: sums, 1: sumsq
  float s = 0.f;
  #pragma unroll 8
  for (int b = 0; b < SBLK; ++b)             // fixed serial order: deterministic
    s += part[(size_t)(b * 2 + sq) * DIM + c];
  (sq ? cq : cs)[c] = s;
}

// ---------------- BatchNorm (train-mode batch stats) + LeakyReLU, in-place safe ----------------
__global__ void __launch_bounds__(256) bn_kernel(
    const float* __restrict__ in, float* __restrict__ out,
    const float* __restrict__ cs, const float* __restrict__ cq,
    const float* __restrict__ gam, const float* __restrict__ bet)
{
  const int tid = threadIdx.x;
  const int c0  = (tid & 63) * 4;
  const int ro  = tid >> 6;
  const float invN = 1.0f / (float)NROWS;
  float sc[4], sh[4];
  #pragma unroll
  for (int j = 0; j < 4; ++j) {
    const int c = c0 + j;
    const float mean = cs[c] * invN;
    const float var  = cq[c] * invN - mean * mean;   // biased var (jnp.var / torch BN)
    const float s    = gam[c] / sqrtf(var + BNEPS);
    sc[j] = s; sh[j] = bet[c] - mean * s;
  }
  const int rbase = blockIdx.x * 128;
  #pragma unroll 4
  for (int it = 0; it < 32; ++it) {
    const int r = rbase + ro + it * 4;
    const float4 v = reinterpret_cast<const float4*>(in + (size_t)r * DIM)[tid & 63];
    float y0 = fmaf(sc[0], v.x, sh[0]);
    float y1 = fmaf(sc[1], v.y, sh[1]);
    float y2 = fmaf(sc[2], v.z, sh[2]);
    float y3 = fmaf(sc[3], v.w, sh[3]);
    y0 = y0 >= 0.f ? y0 : SLOPE * y0;
    y1 = y1 >= 0.f ? y1 : SLOPE * y1;
    y2 = y2 >= 0.f ? y2 : SLOPE * y2;
    y3 = y3 >= 0.f ? y3 : SLOPE * y3;
    const float4 o = {y0, y1, y2, y3};
    reinterpret_cast<float4*>(out + (size_t)r * DIM)[tid & 63] = o;
  }
}

extern "C" void kernel_launch(void* const* d_in, const int* in_sizes, int n_in,
                              void* d_out, int out_size, void* d_ws, size_t ws_size,
                              hipStream_t stream) {
  (void)in_sizes; (void)n_in; (void)out_size; (void)ws_size;
  const float* x    = (const float*)d_in[0];
  const float* mem1 = (const float*)d_in[1];
  const float* mem2 = (const float*)d_in[2];
  const float* g1   = (const float*)d_in[3];
  const float* b1   = (const float*)d_in[4];
  const float* g2   = (const float*)d_in[5];
  const float* b2   = (const float*)d_in[6];
  float* out = (float*)d_out;
  float* ws  = (float*)d_ws;

  // ws layout (floats):
  // minv1[2048] | minv2[2048] | part[SBLK*2*256 = 65536] | cs1[256] cq1[256] cs2[256] cq2[256]
  float* minv1 = ws;
  float* minv2 = ws + 2048;
  float* part  = ws + 4096;
  float* cs1   = ws + 4096 + SBLK * 2 * DIM;        // +65536
  float* cq1   = cs1 + 256;
  float* cs2   = cq1 + 256;
  float* cq2   = cs2 + 256;

  memnorm_kernel<<<(2 * MSIZE) / 4, 256, 0, stream>>>(mem1, mem2, minv1, minv2);

  // unit 1: x -> d_out; deterministic stats; BN1 in place
  unit_kernel<<<NROWS / BM, NTHR, 0, stream>>>(x, mem1, minv1, out);
  stats_part_kernel<<<SBLK, 256, 0, stream>>>(out, part);
  stats_reduce_kernel<<<1, 512, 0, stream>>>(part, cs1, cq1);
  bn_kernel<<<NROWS / 128, 256, 0, stream>>>(out, out, cs1, cq1, g1, b1);

  // unit 2: in-place safe (each block stages its own 64 input rows before overwriting)
  unit_kernel<<<NROWS / BM, NTHR, 0, stream>>>(out, mem2, minv2, out);
  stats_part_kernel<<<SBLK, 256, 0, stream>>>(out, part);
  stats_reduce_kernel<<<1, 512, 0, stream>>>(part, cs2, cq2);
  bn_kernel<<<NROWS / 128, 256, 0, stream>>>(out, out, cs2, cq2, g2, b2);
}